// Round 7
// baseline (150.679 us; speedup 1.0000x reference)
//
#include <hip/hip_runtime.h>

#define NEGV -10000.0f

typedef _Float16 f16x8 __attribute__((ext_vector_type(8)));
typedef _Float16 f16x2 __attribute__((ext_vector_type(2)));
typedef float floatx4 __attribute__((ext_vector_type(4)));

// key (0..319) -> source sequence row. keys 0..63 local to query block nblk,
// keys 64..319 are the 256 global positions {0,61,62,63}+64j.
__device__ __forceinline__ int src_row(int key, int nblk) {
    if (key < 64) return nblk * 64 + key;
    int g = key - 64;
    int p = g & 3;
    return (g >> 2) * 64 + (p ? (60 + p) : 0);
}

__device__ __forceinline__ f16x8 cvt8(const float4& f0, const float4& f1) {
    f16x8 o;
    o[0] = (_Float16)f0.x; o[1] = (_Float16)f0.y;
    o[2] = (_Float16)f0.z; o[3] = (_Float16)f0.w;
    o[4] = (_Float16)f1.x; o[5] = (_Float16)f1.y;
    o[6] = (_Float16)f1.z; o[7] = (_Float16)f1.w;
    return o;
}

// Swapped-QK + key permutation L(t,n) = 32*(t>>1) + 8*(n>>2) + 4*(t&1) + (n&3):
//   acc[t][r] at lane (quad,m) = S[L(t,4*quad+r)][qrow m]; P fragment for PV is
//   a pure in-lane cvt of acc. Tiles 0..3 = local keys, 4..19 = global keys.
// Round 7 (on round-6's persistent slice blocks): ONE barrier per iteration.
//  - local VT double-buffered (2x8KB) -> write(i+1) never waits on reads(i);
//  - local K never touches LDS: each wave prefetches its 4-tile A-fragments
//    to registers one iteration ahead (16 float4, issued under QK, cvt after
//    softmax). LDS = 64KB global images + 16KB LVT dbuf = 80KB, 2 blocks/CU.
//  - softmax reductions ILP-4 (4 independent 20-deep chains, not one 80-deep);
//  - s_setprio(1) around MFMA clusters (2 independent blocks/SIMD -> T5 regime).
__global__ __launch_bounds__(256, 2)
void sparse_attn_kernel(const float* __restrict__ Q, const float* __restrict__ K,
                        const float* __restrict__ V, const float* __restrict__ M,
                        float* __restrict__ O)
{
    const int x     = blockIdx.x;                     // 512 blocks
    const int bh    = (x & 7) * 4 + ((x >> 3) >> 4);  // 4 whole heads per XCD
    const int slice = (x >> 3) & 15;                  // 16 slices per head
    const int b     = bh >> 4;
    const int nblk0 = slice * 4;

    const size_t hoff = (size_t)bh * (4096 * 64);
    const float* Qh = Q + hoff;
    const float* Kh = K + hoff;
    const float* Vh = V + hoff;
    float*       Oh = O + hoff;
    const float* Mb = M + (size_t)b * 4096;

    // 80KB: [0,16384) global K (32 slabs x 512 f16, slab (t-4)*2+c);
    // [16384,32768) global VT (32 slabs, slab (k2-2)*4+t, XOR (t<<4) swizzle);
    // [32768,36864) local VT buf0; [36864,40960) local VT buf1.
    __shared__ _Float16 smem[40960];
    constexpr int GVT = 16384, LVT = 32768;

    const int tid  = threadIdx.x;
    const int lane = tid & 63;
    const int wv   = tid >> 6;          // wave -> query rows wv*16..+15
    const int m    = lane & 15;
    const int quad = lane >> 4;
    const int cg   = tid & 15;          // V col granule (4 floats)
    const int pg   = tid >> 4;          // V key-pair sub-index (0..15)

    // ---- helpers ----
    auto vt_store_at = [&](int base, int k2, const float4& f0, const float4& f1) {
        int td    = cg >> 2;
        int sw    = td << 4;
        int lbase = base + (k2 * 4 + td) * 512 + (pg >> 2) * 128
                  + (cg & 3) * 32 + 2 * (pg & 3);
        f16x2 pk0; pk0[0] = (_Float16)f0.x; pk0[1] = (_Float16)f1.x;
        *(f16x2*)(&smem[(lbase +  0) ^ sw]) = pk0;
        f16x2 pk1; pk1[0] = (_Float16)f0.y; pk1[1] = (_Float16)f1.y;
        *(f16x2*)(&smem[(lbase +  8) ^ sw]) = pk1;
        f16x2 pk2; pk2[0] = (_Float16)f0.z; pk2[1] = (_Float16)f1.z;
        *(f16x2*)(&smem[(lbase + 16) ^ sw]) = pk2;
        f16x2 pk3; pk3[0] = (_Float16)f0.w; pk3[1] = (_Float16)f1.w;
        *(f16x2*)(&smem[(lbase + 24) ^ sw]) = pk3;
    };
    auto q_load = [&](int nblk, float4* qn) {
        const float* src = Qh + (size_t)(nblk * 64 + wv * 16 + m) * 64 + quad * 8;
        qn[0] = *(const float4*)src;        qn[1] = *(const float4*)(src + 4);
        qn[2] = *(const float4*)(src + 32); qn[3] = *(const float4*)(src + 36);
    };
    // local K A-fragments direct to registers: tile t<4, slot c; lane owns
    // row L(t,m), cols c*32 + quad*8 .. +8  (16 float4 per iteration)
    auto lk_load = [&](int nblk, float4* kt) {
        #pragma unroll
        for (int t = 0; t < 4; ++t) {
            int lkey = 32 * (t >> 1) + 8 * (m >> 2) + 4 * (t & 1) + (m & 3);
            const float* row = Kh + (size_t)(nblk * 64 + lkey) * 64 + quad * 8;
            #pragma unroll
            for (int c = 0; c < 2; ++c) {
                kt[(t * 2 + c) * 2]     = *(const float4*)(row + c * 32);
                kt[(t * 2 + c) * 2 + 1] = *(const float4*)(row + c * 32 + 4);
            }
        }
    };
    auto lv_load = [&](int nblk, float4* vv) {
        #pragma unroll
        for (int g = 0; g < 2; ++g) {
            int l0 = 2 * (g * 16 + pg);
            vv[2 * g]     = *(const float4*)(Vh + (size_t)(nblk * 64 + l0) * 64 + cg * 4);
            vv[2 * g + 1] = *(const float4*)(Vh + (size_t)(nblk * 64 + l0 + 1) * 64 + cg * 4);
        }
    };
    auto lv_write = [&](int buf, const float4* vv) {
        vt_store_at(LVT + buf * 4096, 0, vv[0], vv[1]);
        vt_store_at(LVT + buf * 4096, 1, vv[2], vv[3]);
    };

    // ---- mask: global part fixed for the whole block ----
    float mv2[5];
    unsigned long long bbg = 0ull;
    #pragma unroll
    for (int s = 1; s < 5; ++s) {
        float mval = Mb[src_row(s * 64 + lane, 0)];
        bbg |= __ballot(mval == 0.0f);
        mv2[s] = (mval == 0.0f) ? NEGV : 0.0f;
    }

    // ---- prologue: stage global K image (tiles 4..19) ----
    #pragma unroll
    for (int it = 0; it < 8; ++it) {
        int S    = it * 256 + tid;                  // 0..2047
        int t    = (S >> 7) + 4;
        int n    = S & 15;
        int col0 = ((S >> 6) & 1) * 32 + ((S & 63) >> 4) * 8;
        int lkey = 32 * (t >> 1) + 8 * (n >> 2) + 4 * (t & 1) + (n & 3);  // >=64
        const float* src = Kh + (size_t)src_row(lkey, 0) * 64 + col0;
        float4 f0 = *(const float4*)src;
        float4 f1 = *(const float4*)(src + 4);
        *(f16x8*)(&smem[S * 8]) = cvt8(f0, f1);
    }
    // ---- prologue: stage global VT image (keys 64..319) ----
    #pragma unroll
    for (int it = 2; it < 10; ++it) {
        int l0 = 2 * (it * 16 + pg);                // 64..319
        float4 f0 = *(const float4*)(Vh + (size_t)src_row(l0,     0) * 64 + cg * 4);
        float4 f1 = *(const float4*)(Vh + (size_t)src_row(l0 + 1, 0) * 64 + cg * 4);
        vt_store_at(GVT, it - 2, f0, f1);
    }
    // ---- prologue: iter-0 locals ----
    float4 qn[4], ktmp[16], vn[4];
    f16x8 lkf[8];
    q_load(nblk0, qn);
    lk_load(nblk0, ktmp);
    lv_load(nblk0, vn);
    #pragma unroll
    for (int j = 0; j < 8; ++j) lkf[j] = cvt8(ktmp[2 * j], ktmp[2 * j + 1]);
    lv_write(0, vn);
    float mloc = Mb[(size_t)nblk0 * 64 + lane];

    __syncthreads();   // B1: all images complete

    // ---- main loop: 4 qblocks, ONE barrier per iteration ----
    #pragma unroll
    for (int i = 0; i < 4; ++i) {
        const int nblk = nblk0 + i;
        const float mloc_c = mloc;
        f16x8 qf[2] = { cvt8(qn[0], qn[1]), cvt8(qn[2], qn[3]) };

        // QK: 40 MFMA (tiles 0..3 from registers, 4..19 from LDS)
        floatx4 acc[20];
        __builtin_amdgcn_s_setprio(1);
        #pragma unroll
        for (int t = 0; t < 20; ++t) {
            acc[t] = floatx4{0.f, 0.f, 0.f, 0.f};
            #pragma unroll
            for (int c = 0; c < 2; ++c) {
                f16x8 kf;
                if (t < 4) kf = lkf[t * 2 + c];
                else       kf = *(const f16x8*)(&smem[((t - 4) * 2 + c) * 512 + lane * 8]);
                acc[t] = __builtin_amdgcn_mfma_f32_16x16x32_f16(kf, qf[c], acc[t], 0, 0, 0);
            }
        }
        __builtin_amdgcn_s_setprio(0);

        // prefetch next iteration's locals; land under softmax
        if (i < 3) {
            q_load(nblk + 1, qn);
            lk_load(nblk + 1, ktmp);
            lv_load(nblk + 1, vn);
            mloc = Mb[(size_t)(nblk + 1) * 64 + lane];
        }

        // mask slow path
        unsigned long long bb = bbg | __ballot(mloc_c == 0.0f);
        if (bb != 0ull) {
            mv2[0] = (mloc_c == 0.0f) ? NEGV : 0.0f;
            #pragma unroll
            for (int t = 0; t < 20; ++t) {
                int lb = 32 * ((t >> 1) & 1) + 4 * (t & 1) + 8 * quad;
                #pragma unroll
                for (int r = 0; r < 4; ++r)
                    acc[t][r] += __shfl(mv2[t >> 2], lb + r, 64);
            }
        }

        // softmax, ILP-4 (4 independent 20-deep chains per reduction)
        float rmax4[4] = {-3e38f, -3e38f, -3e38f, -3e38f};
        #pragma unroll
        for (int t = 0; t < 20; ++t)
            #pragma unroll
            for (int r = 0; r < 4; ++r)
                rmax4[r] = fmaxf(rmax4[r], acc[t][r]);
        float rmax = fmaxf(fmaxf(rmax4[0], rmax4[1]), fmaxf(rmax4[2], rmax4[3]));
        rmax = fmaxf(rmax, __shfl_xor(rmax, 16, 64));
        rmax = fmaxf(rmax, __shfl_xor(rmax, 32, 64));
        float rsum4[4] = {0.f, 0.f, 0.f, 0.f};
        #pragma unroll
        for (int t = 0; t < 20; ++t)
            #pragma unroll
            for (int r = 0; r < 4; ++r) {
                float e = __expf(acc[t][r] - rmax);
                acc[t][r] = e;
                rsum4[r] += e;
            }
        float rsum = (rsum4[0] + rsum4[1]) + (rsum4[2] + rsum4[3]);
        rsum += __shfl_xor(rsum, 16, 64);
        rsum += __shfl_xor(rsum, 32, 64);
        const float rinv = 1.0f / rsum;

        // rotate next-iter locals into place (no barrier needed here:
        // buffer (i+1)&1 was last read in PV(i-1), fenced by iter-(i-1) barrier)
        if (i < 3) {
            lv_write((i + 1) & 1, vn);
            #pragma unroll
            for (int j = 0; j < 8; ++j) lkf[j] = cvt8(ktmp[2 * j], ktmp[2 * j + 1]);
        }

        // PV: 40 MFMA; P built in-lane per k2 with 1/rowsum folded in
        const int lvbase = LVT + (i & 1) * 4096;
        floatx4 oacc[4] = {};
        __builtin_amdgcn_s_setprio(1);
        #pragma unroll
        for (int k2 = 0; k2 < 10; ++k2) {
            f16x8 p;
            #pragma unroll
            for (int r = 0; r < 4; ++r) {
                p[r]     = (_Float16)(acc[2 * k2][r]     * rinv);
                p[4 + r] = (_Float16)(acc[2 * k2 + 1][r] * rinv);
            }
            #pragma unroll
            for (int t = 0; t < 4; ++t) {
                const int base = (k2 < 2) ? (lvbase + (k2 * 4 + t) * 512)
                                          : (GVT + ((k2 - 2) * 4 + t) * 512);
                f16x8 vf = *(const f16x8*)(&smem[base + ((lane * 8) ^ (t << 4))]);
                oacc[t] = __builtin_amdgcn_mfma_f32_16x16x32_f16(p, vf, oacc[t], 0, 0, 0);
            }
        }
        __builtin_amdgcn_s_setprio(0);

        // store O (P pre-normalized)
        #pragma unroll
        for (int t = 0; t < 4; ++t)
            #pragma unroll
            for (int r = 0; r < 4; ++r)
                Oh[(size_t)(nblk * 64 + wv * 16 + quad * 4 + r) * 64 + t * 16 + m] =
                    oacc[t][r];

        if (i < 3) __syncthreads();   // lv_write(i+1) visible before PV(i+1)
    }
}

extern "C" void kernel_launch(void* const* d_in, const int* in_sizes, int n_in,
                              void* d_out, int out_size, void* d_ws, size_t ws_size,
                              hipStream_t stream) {
    const float* q    = (const float*)d_in[0];
    const float* k    = (const float*)d_in[1];
    const float* v    = (const float*)d_in[2];
    const float* mask = (const float*)d_in[3];
    float* out = (float*)d_out;
    (void)in_sizes; (void)n_in; (void)out_size; (void)d_ws; (void)ws_size;
    sparse_attn_kernel<<<512, 256, 0, stream>>>(q, k, v, mask, out);
}